// Round 8
// baseline (48717.139 us; speedup 1.0000x reference)
//
#include <hip/hip_runtime.h>

#define HIDDEN   2048
#define T_STEPS  8192
#define WASHOUT  200
#define NWG      64
#define NTHR     512
#define NWAVE    (NTHR / 64)                 // 8 waves
#define ROWS_PER_WG   (HIDDEN / NWG)         // 32
#define ROWS_PER_WAVE (ROWS_PER_WG / NWAVE)  // 4
#define NCHUNK   8                           // 8 chunks of 256 state elements

// ws layout: unsigned long long pairs[2][HIDDEN] -- {value:hi32, step:lo32}.
// One 8B atomic carries payload+tag: no fences, no flags, one round trip.
// 0xAA poison -> tag 0xAAAAAAAA never matches a real step: self-initializing.

// Weights live in AGPRs (asm-defined: cannot be rematerialized or refetched).
#define AG_W(dst, src) \
  asm volatile("v_accvgpr_write_b32 %0, %1" : "=a"(dst) : "v"(src))
#define AG_R(dst, src) \
  asm("v_accvgpr_read_b32 %0, %1" : "=v"(dst) : "a"(src))

__global__ __launch_bounds__(NTHR, 1) void esn_main(
    const float* __restrict__ u,
    const float* __restrict__ w_in,
    const float* __restrict__ w_res,
    const float* __restrict__ w_out,
    float* __restrict__ out,
    unsigned long long* __restrict__ pairs)
{
  const int g  = blockIdx.x;    // 0..63, one WG per CU
  const int j  = threadIdx.x;   // 0..511
  const int wv = j >> 6;        // 0..7
  const int l  = j & 63;

  __shared__ float x_s[2][HIDDEN];      // double-buffered staged state (16 KB)
  __shared__ float u_s[T_STEPS];        // 32 KB
  __shared__ float red[2][NWAVE];       // per-wave readout partials, by parity
  __shared__ unsigned cflag[2][NCHUNK]; // per-chunk step tags

#pragma unroll
  for (int k = 0; k < T_STEPS / NTHR; ++k) u_s[j + NTHR * k] = u[j + NTHR * k];
  if (j < 2 * NCHUNK) ((unsigned*)cflag)[j] = 0xFFFFFFFFu;  // never a step id

  // wave wv owns rows r0..r0+3; lane l owns cols {c*256 + 4l .. +3}
  const int r0 = g * ROWS_PER_WG + wv * ROWS_PER_WAVE;

  float wa[ROWS_PER_WAVE][4 * NCHUNK];  // 128 AGPR-resident weights per thread
#pragma unroll
  for (int i = 0; i < ROWS_PER_WAVE; ++i) {
#pragma unroll
    for (int c = 0; c < NCHUNK; ++c) {
      const float4 a = *(const float4*)&w_res[(r0 + i) * HIDDEN + c * 256 + 4 * l];
      AG_W(wa[i][4 * c + 0], a.x); AG_W(wa[i][4 * c + 1], a.y);
      AG_W(wa[i][4 * c + 2], a.z); AG_W(wa[i][4 * c + 3], a.w);
    }
  }

  const float winl = w_in[r0 + (l & 3)];   // valid for lanes 0..3
  const float wol  = w_out[r0 + (l & 3)];

  __syncthreads();  // u_s + cflag init ready (the only full barrier in the loop)

  for (int t = 0; t < T_STEPS; ++t) {
    float d0 = 0.f, d1 = 0.f, d2 = 0.f, d3 = 0.f;
    const unsigned b = (unsigned)((t - 1) & 1);
    if (t > 0) {
      const unsigned want = (unsigned)(t - 1);
      // wave wv polls ONLY its own chunk: lane-contiguous 2 KB span
      const unsigned long long* bp = pairs + b * HIDDEN + (wv << 8) + 4 * l;
      unsigned long long p0, p1, p2, p3;
      for (;;) {
        p0 = __hip_atomic_load(bp + 0, __ATOMIC_RELAXED, __HIP_MEMORY_SCOPE_AGENT);
        p1 = __hip_atomic_load(bp + 1, __ATOMIC_RELAXED, __HIP_MEMORY_SCOPE_AGENT);
        p2 = __hip_atomic_load(bp + 2, __ATOMIC_RELAXED, __HIP_MEMORY_SCOPE_AGENT);
        p3 = __hip_atomic_load(bp + 3, __ATOMIC_RELAXED, __HIP_MEMORY_SCOPE_AGENT);
        if ((((unsigned)p0 == want) & ((unsigned)p1 == want)) &
            (((unsigned)p2 == want) & ((unsigned)p3 == want))) break;
      }
      float4 xv;
      xv.x = __uint_as_float((unsigned)(p0 >> 32));
      xv.y = __uint_as_float((unsigned)(p1 >> 32));
      xv.z = __uint_as_float((unsigned)(p2 >> 32));
      xv.w = __uint_as_float((unsigned)(p3 >> 32));
      *(float4*)&x_s[b][(wv << 8) + 4 * l] = xv;  // one ds_write_b128
      // release: drain the ds_write, then tag the chunk fresh
      if (l == 0)
        __hip_atomic_store(&cflag[b][wv], want, __ATOMIC_RELEASE,
                           __HIP_MEMORY_SCOPE_WORKGROUP);

      // consume chunks as they arrive (static order keeps AGPR idx compile-time)
#pragma unroll
      for (int c = 0; c < NCHUNK; ++c) {
        while (__hip_atomic_load(&cflag[b][c], __ATOMIC_ACQUIRE,
                                 __HIP_MEMORY_SCOPE_WORKGROUP) != want) {}
        const float4 x4 = *(const float4*)&x_s[b][(c << 8) + 4 * l];
        float w;
        AG_R(w, wa[0][4 * c + 0]); d0 = fmaf(w, x4.x, d0);
        AG_R(w, wa[0][4 * c + 1]); d0 = fmaf(w, x4.y, d0);
        AG_R(w, wa[0][4 * c + 2]); d0 = fmaf(w, x4.z, d0);
        AG_R(w, wa[0][4 * c + 3]); d0 = fmaf(w, x4.w, d0);
        AG_R(w, wa[1][4 * c + 0]); d1 = fmaf(w, x4.x, d1);
        AG_R(w, wa[1][4 * c + 1]); d1 = fmaf(w, x4.y, d1);
        AG_R(w, wa[1][4 * c + 2]); d1 = fmaf(w, x4.z, d1);
        AG_R(w, wa[1][4 * c + 3]); d1 = fmaf(w, x4.w, d1);
        AG_R(w, wa[2][4 * c + 0]); d2 = fmaf(w, x4.x, d2);
        AG_R(w, wa[2][4 * c + 1]); d2 = fmaf(w, x4.y, d2);
        AG_R(w, wa[2][4 * c + 2]); d2 = fmaf(w, x4.z, d2);
        AG_R(w, wa[2][4 * c + 3]); d2 = fmaf(w, x4.w, d2);
        AG_R(w, wa[3][4 * c + 0]); d3 = fmaf(w, x4.x, d3);
        AG_R(w, wa[3][4 * c + 1]); d3 = fmaf(w, x4.y, d3);
        AG_R(w, wa[3][4 * c + 2]); d3 = fmaf(w, x4.z, d3);
        AG_R(w, wa[3][4 * c + 3]); d3 = fmaf(w, x4.w, d3);
      }
    }

    // tree-combine reduce: 10 shuffles; lane l ends with row (l&3)'s full sum
    float e0 = d0 + __shfl_xor(d0, 1, 64);
    float e1 = d1 + __shfl_xor(d1, 1, 64);
    float e2 = d2 + __shfl_xor(d2, 1, 64);
    float e3 = d3 + __shfl_xor(d3, 1, 64);
    float f0 = (l & 1) ? e1 : e0;
    float f1 = (l & 1) ? e3 : e2;
    f0 += __shfl_xor(f0, 2, 64);
    f1 += __shfl_xor(f1, 2, 64);
    float h = (l & 2) ? f1 : f0;
    h += __shfl_xor(h, 4, 64);
    h += __shfl_xor(h, 8, 64);
    h += __shfl_xor(h, 16, 64);
    h += __shfl_xor(h, 32, 64);

    const float ut = u_s[t];
    float xn = 0.f;
    if (l < ROWS_PER_WAVE) {
      xn = tanhf(fmaf(winl, ut, h));
      const unsigned long long pk =
          ((unsigned long long)__float_as_uint(xn) << 32) | (unsigned)t;
      __hip_atomic_store(pairs + (t & 1) * HIDDEN + r0 + l, pk,
                         __ATOMIC_RELAXED, __HIP_MEMORY_SCOPE_AGENT);
    }

    // distributed readout partial of x_t . w_out (this WG's 4 rows per wave)
    float part = xn * wol;                     // 0 for lanes >= 4
    part += __shfl_down(part, 2, 64);
    part += __shfl_down(part, 1, 64);          // lane0 = rows r0..r0+3
    if (l == 0) red[t & 1][wv] = part;

    // flush step t-1's partial. Safe: wave0 saw cflag[b][c]==t-1 for all c,
    // and each wave set its flag only AFTER its step-(t-1) red write (release).
    if (t >= WASHOUT + 1 && j == 0) {
      const float* rp = red[b];
      float s = ((rp[0] + rp[1]) + (rp[2] + rp[3])) +
                ((rp[4] + rp[5]) + (rp[6] + rp[7]));
      atomicAdd(&out[t - 1 - WASHOUT], s);
    }
  }

  // epilogue: flush the final step's partial
  __syncthreads();
  if (j == 0) {
    const float* rp = red[(T_STEPS - 1) & 1];
    float s = ((rp[0] + rp[1]) + (rp[2] + rp[3])) +
              ((rp[4] + rp[5]) + (rp[6] + rp[7]));
    atomicAdd(&out[T_STEPS - 1 - WASHOUT], s);
  }
}

extern "C" void kernel_launch(void* const* d_in, const int* in_sizes, int n_in,
                              void* d_out, int out_size, void* d_ws, size_t ws_size,
                              hipStream_t stream) {
  const float* u     = (const float*)d_in[0];
  const float* w_in  = (const float*)d_in[1];
  const float* w_res = (const float*)d_in[2];
  const float* w_out = (const float*)d_in[3];
  float* out = (float*)d_out;
  unsigned long long* pairs = (unsigned long long*)d_ws;

  // out accumulates atomicAdd partials -> must start at zero every call
  hipMemsetAsync(out, 0, (size_t)out_size * sizeof(float), stream);
  esn_main<<<NWG, NTHR, 0, stream>>>(u, w_in, w_res, w_out, out, pairs);
}

// Round 9
// 18710.971 us; speedup vs baseline: 2.6037x; 2.6037x over previous
//
#include <hip/hip_runtime.h>

#define HIDDEN   2048
#define T_STEPS  8192
#define WASHOUT  200
#define NWG      64
#define NTHR     512
#define NWAVE    (NTHR / 64)                 // 8 waves
#define ROWS_PER_WG   (HIDDEN / NWG)         // 32
#define ROWS_PER_WAVE (ROWS_PER_WG / NWAVE)  // 4
#define NCHUNK   8                           // 8 chunks of 256 state elements

// ws layout: unsigned long long pairs[2][HIDDEN] -- {value:hi32, step:lo32}.
// One 8B unit carries payload+tag: no fences, no flags, one round trip.
// 0xAA poison -> tag 0xAAAAAAAA never matches a real step: self-initializing.

// Weights live in AGPRs (asm-defined: cannot be rematerialized or refetched).
#define AG_W(dst, src) \
  asm volatile("v_accvgpr_write_b32 %0, %1" : "=a"(dst) : "v"(src))
#define AG_R(dst, src) \
  asm("v_accvgpr_read_b32 %0, %1" : "=v"(dst) : "a"(src))

typedef unsigned uint4v __attribute__((ext_vector_type(4)));

__global__ __launch_bounds__(NTHR, 1) void esn_main(
    const float* __restrict__ u,
    const float* __restrict__ w_in,
    const float* __restrict__ w_res,
    const float* __restrict__ w_out,
    float* __restrict__ out,
    unsigned long long* __restrict__ pairs)
{
  const int g  = blockIdx.x;    // 0..63, one WG per CU
  const int j  = threadIdx.x;   // 0..511
  const int wv = j >> 6;        // 0..7
  const int l  = j & 63;

  __shared__ float x_s[2][HIDDEN];      // double-buffered staged state (16 KB)
  __shared__ float u_s[T_STEPS];        // 32 KB
  __shared__ float fresh[ROWS_PER_WG];  // this WG's newest 32 values

#pragma unroll
  for (int k = 0; k < T_STEPS / NTHR; ++k) u_s[j + NTHR * k] = u[j + NTHR * k];

  // wave wv owns rows r0..r0+3; lane l owns cols {c*256 + 4l .. +3}
  const int r0 = g * ROWS_PER_WG + wv * ROWS_PER_WAVE;

  float wa[ROWS_PER_WAVE][4 * NCHUNK];  // 128 AGPR-resident weights per thread
#pragma unroll
  for (int i = 0; i < ROWS_PER_WAVE; ++i) {
#pragma unroll
    for (int c = 0; c < NCHUNK; ++c) {
      const float4 a = *(const float4*)&w_res[(r0 + i) * HIDDEN + c * 256 + 4 * l];
      AG_W(wa[i][4 * c + 0], a.x); AG_W(wa[i][4 * c + 1], a.y);
      AG_W(wa[i][4 * c + 2], a.z); AG_W(wa[i][4 * c + 3], a.w);
    }
  }

  const float winl = w_in[r0 + (l & 3)];                       // lanes 0..3
  const float wol  = (wv == 1 && l < 32) ? w_out[g * 32 + l] : 0.f;  // wave 1

  __syncthreads();  // u_s ready

  for (int t = 0; t < T_STEPS; ++t) {
    float d0 = 0.f, d1 = 0.f, d2 = 0.f, d3 = 0.f;
    const unsigned b = (unsigned)((t - 1) & 1);
    if (t > 0) {
      const unsigned want = (unsigned)(t - 1);
      // wave wv polls only its own chunk; 2x16B L2-bypassing loads per round
      const unsigned long long* bp = pairs + b * HIDDEN + (wv << 8) + 4 * l;
      uint4v A, B;   // [tag0, val0, tag1, val1]
      for (;;) {
        asm volatile(
            "global_load_dwordx4 %0, %2, off sc1\n\t"
            "global_load_dwordx4 %1, %3, off sc1\n\t"
            "s_waitcnt vmcnt(0)"
            : "=&v"(A), "=&v"(B)
            : "v"(bp), "v"(bp + 2)
            : "memory");
        if (((A.x == want) & (A.z == want)) &
            ((B.x == want) & (B.z == want))) break;
      }
      float4 xv;
      xv.x = __uint_as_float(A.y);
      xv.y = __uint_as_float(A.w);
      xv.z = __uint_as_float(B.y);
      xv.w = __uint_as_float(B.w);
      *(float4*)&x_s[b][(wv << 8) + 4 * l] = xv;  // one ds_write_b128
    }
    __syncthreads();  // barrier 1: all chunks staged

    if (t > 0) {
      const float4* xs4 = (const float4*)x_s[b];
#pragma unroll
      for (int c = 0; c < NCHUNK; ++c) {
        const float4 x4 = xs4[(c << 6) + l];   // ds_read_b128
        float w;
        AG_R(w, wa[0][4 * c + 0]); d0 = fmaf(w, x4.x, d0);
        AG_R(w, wa[0][4 * c + 1]); d0 = fmaf(w, x4.y, d0);
        AG_R(w, wa[0][4 * c + 2]); d0 = fmaf(w, x4.z, d0);
        AG_R(w, wa[0][4 * c + 3]); d0 = fmaf(w, x4.w, d0);
        AG_R(w, wa[1][4 * c + 0]); d1 = fmaf(w, x4.x, d1);
        AG_R(w, wa[1][4 * c + 1]); d1 = fmaf(w, x4.y, d1);
        AG_R(w, wa[1][4 * c + 2]); d1 = fmaf(w, x4.z, d1);
        AG_R(w, wa[1][4 * c + 3]); d1 = fmaf(w, x4.w, d1);
        AG_R(w, wa[2][4 * c + 0]); d2 = fmaf(w, x4.x, d2);
        AG_R(w, wa[2][4 * c + 1]); d2 = fmaf(w, x4.y, d2);
        AG_R(w, wa[2][4 * c + 2]); d2 = fmaf(w, x4.z, d2);
        AG_R(w, wa[2][4 * c + 3]); d2 = fmaf(w, x4.w, d2);
        AG_R(w, wa[3][4 * c + 0]); d3 = fmaf(w, x4.x, d3);
        AG_R(w, wa[3][4 * c + 1]); d3 = fmaf(w, x4.y, d3);
        AG_R(w, wa[3][4 * c + 2]); d3 = fmaf(w, x4.z, d3);
        AG_R(w, wa[3][4 * c + 3]); d3 = fmaf(w, x4.w, d3);
      }
    }

    // tree-combine reduce: 10 shuffles; lane l ends with row (l&3)'s full sum
    float e0 = d0 + __shfl_xor(d0, 1, 64);
    float e1 = d1 + __shfl_xor(d1, 1, 64);
    float e2 = d2 + __shfl_xor(d2, 1, 64);
    float e3 = d3 + __shfl_xor(d3, 1, 64);
    float f0 = (l & 1) ? e1 : e0;
    float f1 = (l & 1) ? e3 : e2;
    f0 += __shfl_xor(f0, 2, 64);
    f1 += __shfl_xor(f1, 2, 64);
    float h = (l & 2) ? f1 : f0;
    h += __shfl_xor(h, 4, 64);
    h += __shfl_xor(h, 8, 64);
    h += __shfl_xor(h, 16, 64);
    h += __shfl_xor(h, 32, 64);

    const float ut = u_s[t];
    if (l < ROWS_PER_WAVE) {
      fresh[wv * ROWS_PER_WAVE + l] = tanhf(fmaf(winl, ut, h));
    }
    __syncthreads();  // barrier 2: fresh[] complete

    if (wv == 0) {
      // consolidated publish: one 32-lane 256B store for the whole WG
      if (l < ROWS_PER_WG) {
        const unsigned long long pk =
            ((unsigned long long)__float_as_uint(fresh[l]) << 32) | (unsigned)t;
        __hip_atomic_store(pairs + (t & 1) * HIDDEN + g * ROWS_PER_WG + l, pk,
                           __ATOMIC_RELAXED, __HIP_MEMORY_SCOPE_AGENT);
      }
    } else if (wv == 1 && t >= WASHOUT) {
      // distributed readout: this WG's 32-row partial of x_t . w_out
      float part = (l < 32) ? fresh[l] * wol : 0.f;
      part += __shfl_xor(part, 32, 64);
      part += __shfl_xor(part, 16, 64);
      part += __shfl_xor(part, 8, 64);
      part += __shfl_xor(part, 4, 64);
      part += __shfl_xor(part, 2, 64);
      part += __shfl_xor(part, 1, 64);
      if (l == 0) atomicAdd(&out[t - WASHOUT], part);
    }
  }
}

extern "C" void kernel_launch(void* const* d_in, const int* in_sizes, int n_in,
                              void* d_out, int out_size, void* d_ws, size_t ws_size,
                              hipStream_t stream) {
  const float* u     = (const float*)d_in[0];
  const float* w_in  = (const float*)d_in[1];
  const float* w_res = (const float*)d_in[2];
  const float* w_out = (const float*)d_in[3];
  float* out = (float*)d_out;
  unsigned long long* pairs = (unsigned long long*)d_ws;

  // out accumulates atomicAdd partials -> must start at zero every call
  hipMemsetAsync(out, 0, (size_t)out_size * sizeof(float), stream);
  esn_main<<<NWG, NTHR, 0, stream>>>(u, w_in, w_res, w_out, out, pairs);
}